// Round 1
// baseline (250.355 us; speedup 1.0000x reference)
//
#include <hip/hip_runtime.h>

#define INF_F 3.402823466e+38f

struct Params {
  const float* points;
  const int* idx[4];
  const float* feats[4];
  float4* centers;
  float* partD;
  int* partI;
  float* wfin;
  int* ifin;
  float* outp;
  int N, totM, totC, nChunks;
  int M[4], C[4], cenOff[4], P[4], chunkLen[4], partOff[4], colOff[4], blkStart[5];
  float ve[4], hv[4];
  float off;
};

// ---------------- kernel 1: voxel index -> metric center (float4) ----------
__global__ __launch_bounds__(256) void centers_kernel(Params pr) {
#pragma clang fp contract(off)
  int t = blockIdx.x * blockDim.x + threadIdx.x;
  if (t >= pr.totM) return;
  int s = (t >= pr.cenOff[1]) + (t >= pr.cenOff[2]) + (t >= pr.cenOff[3]);
  int m = t - pr.cenOff[s];
  const int* id = pr.idx[s] + (size_t)m * 4;
  float ve = pr.ve[s], hv = pr.hv[s], off = pr.off;
  float4 q;
  q.x = ((float)id[1] * ve + off) + hv;   // exact reference op order, no fma
  q.y = ((float)id[2] * ve + off) + hv;
  q.z = ((float)id[3] * ve + off) + hv;
  q.w = 0.0f;
  pr.centers[t] = q;
}

// ---------------- kernel 2: brute-force partial top-3 scan ------------------
__global__ __launch_bounds__(256) void scan_kernel(Params pr) {
#pragma clang fp contract(off)
  int b = blockIdx.x;
  int s = (b >= pr.blkStart[1]) + (b >= pr.blkStart[2]) + (b >= pr.blkStart[3]);
  int rel = b - pr.blkStart[s];
  int part = rel / pr.nChunks;          // block-uniform
  int chunk = rel - part * pr.nChunks;
  int n = chunk * 256 + threadIdx.x;
  bool active = n < pr.N;
  int nn = active ? n : 0;
  float px = pr.points[nn * 3 + 0];
  float py = pr.points[nn * 3 + 1];
  float pz = pr.points[nn * 3 + 2];
  int base = part * pr.chunkLen[s];
  int L = pr.M[s] - base;
  if (L > pr.chunkLen[s]) L = pr.chunkLen[s];
  const float4* cen = pr.centers + pr.cenOff[s] + base;  // uniform base -> s_load

  float b0 = INF_F, b1 = INF_F, b2 = INF_F;
  int i0 = 0, i1 = 0, i2 = 0;
  for (int j = 0; j < L; ++j) {
    float4 q = cen[j];
    float dx = px - q.x, dy = py - q.y, dz = pz - q.z;
    float d = (dx * dx + dy * dy) + dz * dz;   // reference sum order
    if (d < b2) {                               // strict <: stable tie-break
      bool lt1 = d < b1, lt0 = d < b0;
      int jj = base + j;
      b2 = lt1 ? b1 : d;  i2 = lt1 ? i1 : jj;
      b1 = lt0 ? b0 : (lt1 ? d : b1);
      i1 = lt0 ? i0 : (lt1 ? jj : i1);
      b0 = lt0 ? d : b0;  i0 = lt0 ? jj : i0;
    }
  }
  if (active) {
    size_t po = (size_t)pr.partOff[s] + ((size_t)part * pr.N + n) * 3;
    pr.partD[po + 0] = b0; pr.partD[po + 1] = b1; pr.partD[po + 2] = b2;
    pr.partI[po + 0] = i0; pr.partI[po + 1] = i1; pr.partI[po + 2] = i2;
  }
}

// ---------------- kernel 3: merge partials -> weights + indices -------------
__global__ __launch_bounds__(256) void merge_kernel(Params pr) {
#pragma clang fp contract(off)
  int t = blockIdx.x * blockDim.x + threadIdx.x;
  if (t >= 4 * pr.N) return;
  int s = t / pr.N;
  int n = t - s * pr.N;
  float b0 = INF_F, b1 = INF_F, b2 = INF_F;
  int i0 = 0, i1 = 0, i2 = 0;
  int P = pr.P[s];
  for (int p = 0; p < P; ++p) {
    size_t po = (size_t)pr.partOff[s] + ((size_t)p * pr.N + n) * 3;
    for (int k = 0; k < 3; ++k) {
      float d = pr.partD[po + k];
      int i = pr.partI[po + k];
      // candidates arrive in ascending-index order -> strict < keeps stable order
      if (d < b2) {
        bool lt1 = d < b1, lt0 = d < b0;
        b2 = lt1 ? b1 : d;  i2 = lt1 ? i1 : i;
        b1 = lt0 ? b0 : (lt1 ? d : b1);
        i1 = lt0 ? i0 : (lt1 ? i : i1);
        b0 = lt0 ? d : b0;  i0 = lt0 ? i : i0;
      }
    }
  }
  float r0 = 1.0f / (b0 + 1e-8f);
  float r1 = 1.0f / (b1 + 1e-8f);
  float r2 = 1.0f / (b2 + 1e-8f);
  float sum = (r0 + r1) + r2;
  float w0 = r0 / sum, w1 = r1 / sum, w2 = r2 / sum;
  size_t wo = ((size_t)s * pr.N + n) * 3;
  pr.wfin[wo + 0] = w0; pr.wfin[wo + 1] = w1; pr.wfin[wo + 2] = w2;
  pr.ifin[wo + 0] = i0; pr.ifin[wo + 1] = i1; pr.ifin[wo + 2] = i2;
}

// ---------------- kernel 4: weighted feature gather -------------------------
__global__ __launch_bounds__(256) void gather_kernel(Params pr) {
#pragma clang fp contract(off)
  long long t = (long long)blockIdx.x * blockDim.x + threadIdx.x;
  long long tot = (long long)pr.N * pr.totC;
  if (t >= tot) return;
  int n = (int)(t / pr.totC);
  int c = (int)(t - (long long)n * pr.totC);
  int s = (c >= pr.colOff[1]) + (c >= pr.colOff[2]) + (c >= pr.colOff[3]);
  int cc = c - pr.colOff[s];
  size_t wo = ((size_t)s * pr.N + n) * 3;
  float w0 = pr.wfin[wo + 0], w1 = pr.wfin[wo + 1], w2 = pr.wfin[wo + 2];
  int i0 = pr.ifin[wo + 0], i1 = pr.ifin[wo + 1], i2 = pr.ifin[wo + 2];
  const float* F = pr.feats[s];
  int C = pr.C[s];
  float v = (w0 * F[(size_t)i0 * C + cc] + w1 * F[(size_t)i1 * C + cc])
            + w2 * F[(size_t)i2 * C + cc];
  pr.outp[t] = v;
}

extern "C" void kernel_launch(void* const* d_in, const int* in_sizes, int n_in,
                              void* d_out, int out_size, void* d_ws, size_t ws_size,
                              hipStream_t stream) {
  (void)n_in; (void)out_size;
  Params pr;
  pr.points = (const float*)d_in[0];
  pr.N = in_sizes[0] / 3;
  static const int SC[4] = {2, 4, 8, 16};
  int totM = 0, totC = 0;
  for (int s = 0; s < 4; ++s) {
    pr.idx[s] = (const int*)d_in[2 + 2 * s];
    pr.feats[s] = (const float*)d_in[3 + 2 * s];
    pr.M[s] = in_sizes[2 + 2 * s] / 4;
    pr.C[s] = in_sizes[3 + 2 * s] / pr.M[s];
    pr.cenOff[s] = totM;
    pr.colOff[s] = totC;
    totM += pr.M[s];
    totC += pr.C[s];
    float ve = 0.015f * (float)SC[s];
    pr.ve[s] = ve;
    pr.hv[s] = 0.5f * ve;
  }
  pr.off = (-0.5f * 0.015f) * 64.0f;   // exact f32 replication of OFFSET
  pr.totM = totM;
  pr.totC = totC;
  pr.nChunks = (pr.N + 255) / 256;

  // choose partition size; shrink P if workspace is tight
  int chunkTarget = 1000;
  int partTriples = 0, blocks = 0;
  size_t need = 0;
  for (int attempt = 0; attempt < 8; ++attempt) {
    partTriples = 0; blocks = 0;
    for (int s = 0; s < 4; ++s) {
      int P = (pr.M[s] + chunkTarget - 1) / chunkTarget;
      if (P < 1) P = 1;
      pr.P[s] = P;
      pr.chunkLen[s] = (pr.M[s] + P - 1) / P;
      pr.blkStart[s] = blocks;
      blocks += P * pr.nChunks;
      pr.partOff[s] = partTriples * 3;
      partTriples += P * pr.N;
    }
    pr.blkStart[4] = blocks;
    need = (size_t)totM * 16 + (size_t)partTriples * 3 * 8 + (size_t)4 * pr.N * 3 * 8;
    if (need <= ws_size || chunkTarget >= 64000) break;
    chunkTarget *= 4;
  }

  char* ws = (char*)d_ws;
  size_t o = 0;
  pr.centers = (float4*)(ws + o); o += (size_t)totM * 16;
  pr.partD = (float*)(ws + o);    o += (size_t)partTriples * 3 * 4;
  pr.partI = (int*)(ws + o);      o += (size_t)partTriples * 3 * 4;
  pr.wfin = (float*)(ws + o);     o += (size_t)4 * pr.N * 3 * 4;
  pr.ifin = (int*)(ws + o);       o += (size_t)4 * pr.N * 3 * 4;
  pr.outp = (float*)d_out;

  hipLaunchKernelGGL(centers_kernel, dim3((totM + 255) / 256), dim3(256), 0, stream, pr);
  hipLaunchKernelGGL(scan_kernel, dim3(blocks), dim3(256), 0, stream, pr);
  hipLaunchKernelGGL(merge_kernel, dim3((4 * pr.N + 255) / 256), dim3(256), 0, stream, pr);
  long long totOut = (long long)pr.N * totC;
  hipLaunchKernelGGL(gather_kernel, dim3((int)((totOut + 255) / 256)), dim3(256), 0, stream, pr);
}

// Round 2
// 184.409 us; speedup vs baseline: 1.3576x; 1.3576x over previous
//
#include <hip/hip_runtime.h>

#define INF_F 3.402823466e+38f

struct Params {
  const float* points;
  const int* idx[4];
  const float* feats[4];
  float4* centers;
  float* partD;
  int* partI;
  float* wfin;
  int* ifin;
  int* perm;
  float* outp;
  int N, totM, totC, nChunks;
  int M[4], C[4], cenOff[4], P[4], chunkLen[4], partOff[4], colOff[4], blkStart[5];
  float ve[4], hv[4];
  float off;
};

// ---------------- kernel 1: voxel index -> metric center (float4) ----------
__global__ __launch_bounds__(256) void centers_kernel(Params pr) {
#pragma clang fp contract(off)
  int t = blockIdx.x * blockDim.x + threadIdx.x;
  if (t >= pr.totM) return;
  int s = (t >= pr.cenOff[1]) + (t >= pr.cenOff[2]) + (t >= pr.cenOff[3]);
  int m = t - pr.cenOff[s];
  const int* id = pr.idx[s] + (size_t)m * 4;
  float ve = pr.ve[s], hv = pr.hv[s], off = pr.off;
  float4 q;
  q.x = ((float)id[1] * ve + off) + hv;   // exact reference op order, no fma
  q.y = ((float)id[2] * ve + off) + hv;
  q.z = ((float)id[3] * ve + off) + hv;
  q.w = 0.0f;
  pr.centers[t] = q;
}

// ---------------- kernel 1b: Morton bucket-sort of points (1 block) ---------
__device__ __forceinline__ int spread3(int v) {
  return (v & 1) | ((v & 2) << 2) | ((v & 4) << 4) | ((v & 8) << 6);
}

__device__ __forceinline__ int point_bucket(const float* pts, int i) {
  float x = pts[i * 3 + 0], y = pts[i * 3 + 1], z = pts[i * 3 + 2];
  float sc = 16.0f / 0.96f;
  int cx = (int)((x + 0.48f) * sc);
  int cy = (int)((y + 0.48f) * sc);
  int cz = (int)((z + 0.48f) * sc);
  cx = cx < 0 ? 0 : (cx > 15 ? 15 : cx);
  cy = cy < 0 ? 0 : (cy > 15 ? 15 : cy);
  cz = cz < 0 ? 0 : (cz > 15 ? 15 : cz);
  return spread3(cx) | (spread3(cy) << 1) | (spread3(cz) << 2);  // 12-bit morton
}

__global__ __launch_bounds__(1024) void sort_kernel(Params pr) {
  __shared__ int hist[4096];
  __shared__ int partial[1024];
  int tid = threadIdx.x;
  for (int i = tid; i < 4096; i += 1024) hist[i] = 0;
  __syncthreads();
  for (int i = tid; i < pr.N; i += 1024)
    atomicAdd(&hist[point_bucket(pr.points, i)], 1);
  __syncthreads();
  int h0 = hist[4 * tid + 0], h1 = hist[4 * tid + 1];
  int h2 = hist[4 * tid + 2], h3 = hist[4 * tid + 3];
  int mySum = h0 + h1 + h2 + h3;
  partial[tid] = mySum;
  __syncthreads();
  for (int off = 1; off < 1024; off <<= 1) {
    int v = (tid >= off) ? partial[tid - off] : 0;
    __syncthreads();
    partial[tid] += v;
    __syncthreads();
  }
  int excl = partial[tid] - mySum;
  hist[4 * tid + 0] = excl;
  hist[4 * tid + 1] = excl + h0;
  hist[4 * tid + 2] = excl + h0 + h1;
  hist[4 * tid + 3] = excl + h0 + h1 + h2;
  __syncthreads();
  for (int i = tid; i < pr.N; i += 1024) {
    int pos = atomicAdd(&hist[point_bucket(pr.points, i)], 1);
    pr.perm[pos] = i;
  }
}

// ---------------- kernel 2: brute-force partial top-3 scan ------------------
#define STAGE_CAP 1024

__global__ __launch_bounds__(256) void scan_kernel(Params pr) {
#pragma clang fp contract(off)
  __shared__ float4 lds[STAGE_CAP];
  int b = blockIdx.x;
  int s = (b >= pr.blkStart[1]) + (b >= pr.blkStart[2]) + (b >= pr.blkStart[3]);
  int rel = b - pr.blkStart[s];
  int part = rel / pr.nChunks;          // block-uniform
  int chunk = rel - part * pr.nChunks;
  int n = chunk * 256 + threadIdx.x;
  bool active = n < pr.N;
  int pid = active ? pr.perm[n] : 0;
  float px = pr.points[pid * 3 + 0];
  float py = pr.points[pid * 3 + 1];
  float pz = pr.points[pid * 3 + 2];
  int base = part * pr.chunkLen[s];
  int L = pr.M[s] - base;
  if (L > pr.chunkLen[s]) L = pr.chunkLen[s];
  const float4* cen = pr.centers + pr.cenOff[s] + base;

  float bd0 = INF_F, bd1 = INF_F, bd2 = INF_F;
  int bi0 = 0, bi1 = 0, bi2 = 0;

  auto ins = [&](float d, int gi) {   // caller guarantees d < bd2; strict < = stable
    bool lt1 = d < bd1, lt0 = d < bd0;
    bd2 = lt1 ? bd1 : d;  bi2 = lt1 ? bi1 : gi;
    bd1 = lt0 ? bd0 : (lt1 ? d : bd1);
    bi1 = lt0 ? bi0 : (lt1 ? gi : bi1);
    bd0 = lt0 ? d : bd0; bi0 = lt0 ? gi : bi0;
  };

  for (int cb = 0; cb < L; cb += STAGE_CAP) {
    int Lc = L - cb;
    if (Lc > STAGE_CAP) Lc = STAGE_CAP;
    __syncthreads();
    for (int jj = threadIdx.x; jj < Lc; jj += 256) lds[jj] = cen[cb + jj];
    __syncthreads();
    int gbase = base + cb;
    int j = 0;
    for (; j + 8 <= Lc; j += 8) {
      float d[8];
#pragma unroll
      for (int k = 0; k < 8; ++k) {
        float4 q = lds[j + k];
        float dx = px - q.x, dy = py - q.y, dz = pz - q.z;
        d[k] = (dx * dx + dy * dy) + dz * dz;   // reference op order
      }
      float m01 = fminf(d[0], d[1]), m23 = fminf(d[2], d[3]);
      float m45 = fminf(d[4], d[5]), m67 = fminf(d[6], d[7]);
      float m = fminf(fminf(m01, m23), fminf(m45, m67));
      if (m < bd2) {
#pragma unroll
        for (int k = 0; k < 8; ++k)
          if (d[k] < bd2) ins(d[k], gbase + j + k);
      }
    }
    for (; j < Lc; ++j) {
      float4 q = lds[j];
      float dx = px - q.x, dy = py - q.y, dz = pz - q.z;
      float d = (dx * dx + dy * dy) + dz * dz;
      if (d < bd2) ins(d, gbase + j);
    }
  }

  if (active) {
    size_t po = (size_t)pr.partOff[s] + ((size_t)part * pr.N + n) * 3;
    pr.partD[po + 0] = bd0; pr.partD[po + 1] = bd1; pr.partD[po + 2] = bd2;
    pr.partI[po + 0] = bi0; pr.partI[po + 1] = bi1; pr.partI[po + 2] = bi2;
  }
}

// ---------------- kernel 3: merge partials -> weights + indices -------------
__global__ __launch_bounds__(256) void merge_kernel(Params pr) {
#pragma clang fp contract(off)
  int t = blockIdx.x * blockDim.x + threadIdx.x;
  if (t >= 4 * pr.N) return;
  int s = t / pr.N;
  int n = t - s * pr.N;
  float bd0 = INF_F, bd1 = INF_F, bd2 = INF_F;
  int bi0 = 0, bi1 = 0, bi2 = 0;
  int P = pr.P[s];
  for (int p = 0; p < P; ++p) {
    size_t po = (size_t)pr.partOff[s] + ((size_t)p * pr.N + n) * 3;
    for (int k = 0; k < 3; ++k) {
      float d = pr.partD[po + k];
      int i = pr.partI[po + k];
      // candidates arrive in ascending-index order -> strict < keeps stable order
      if (d < bd2) {
        bool lt1 = d < bd1, lt0 = d < bd0;
        bd2 = lt1 ? bd1 : d;  bi2 = lt1 ? bi1 : i;
        bd1 = lt0 ? bd0 : (lt1 ? d : bd1);
        bi1 = lt0 ? bi0 : (lt1 ? i : bi1);
        bd0 = lt0 ? d : bd0; bi0 = lt0 ? i : bi0;
      }
    }
  }
  float r0 = 1.0f / (bd0 + 1e-8f);
  float r1 = 1.0f / (bd1 + 1e-8f);
  float r2 = 1.0f / (bd2 + 1e-8f);
  float sum = (r0 + r1) + r2;
  float w0 = r0 / sum, w1 = r1 / sum, w2 = r2 / sum;
  size_t wo = ((size_t)s * pr.N + n) * 3;
  pr.wfin[wo + 0] = w0; pr.wfin[wo + 1] = w1; pr.wfin[wo + 2] = w2;
  pr.ifin[wo + 0] = bi0; pr.ifin[wo + 1] = bi1; pr.ifin[wo + 2] = bi2;
}

// ---------------- kernel 4: weighted feature gather (block per point) -------
__global__ __launch_bounds__(128) void gather_kernel(Params pr) {
#pragma clang fp contract(off)
  int n = blockIdx.x;                  // sorted slot
  int pid = pr.perm[n];                // original point row
  int nC4 = pr.totC >> 2;
  for (int c4 = threadIdx.x; c4 < nC4; c4 += 128) {
    int c = c4 << 2;
    int s = (c >= pr.colOff[1]) + (c >= pr.colOff[2]) + (c >= pr.colOff[3]);
    int cc = c - pr.colOff[s];
    size_t wo = ((size_t)s * pr.N + n) * 3;
    float w0 = pr.wfin[wo + 0], w1 = pr.wfin[wo + 1], w2 = pr.wfin[wo + 2];
    int i0 = pr.ifin[wo + 0], i1 = pr.ifin[wo + 1], i2 = pr.ifin[wo + 2];
    const float* F = pr.feats[s];
    int C = pr.C[s];
    const float4 a = *(const float4*)(F + (size_t)i0 * C + cc);
    const float4 bq = *(const float4*)(F + (size_t)i1 * C + cc);
    const float4 cq = *(const float4*)(F + (size_t)i2 * C + cc);
    float4 v;
    v.x = (w0 * a.x + w1 * bq.x) + w2 * cq.x;
    v.y = (w0 * a.y + w1 * bq.y) + w2 * cq.y;
    v.z = (w0 * a.z + w1 * bq.z) + w2 * cq.z;
    v.w = (w0 * a.w + w1 * bq.w) + w2 * cq.w;
    *(float4*)(pr.outp + (size_t)pid * pr.totC + c) = v;
  }
}

extern "C" void kernel_launch(void* const* d_in, const int* in_sizes, int n_in,
                              void* d_out, int out_size, void* d_ws, size_t ws_size,
                              hipStream_t stream) {
  (void)n_in; (void)out_size;
  Params pr;
  pr.points = (const float*)d_in[0];
  pr.N = in_sizes[0] / 3;
  static const int SC[4] = {2, 4, 8, 16};
  int totM = 0, totC = 0;
  for (int s = 0; s < 4; ++s) {
    pr.idx[s] = (const int*)d_in[2 + 2 * s];
    pr.feats[s] = (const float*)d_in[3 + 2 * s];
    pr.M[s] = in_sizes[2 + 2 * s] / 4;
    pr.C[s] = in_sizes[3 + 2 * s] / pr.M[s];
    pr.cenOff[s] = totM;
    pr.colOff[s] = totC;
    totM += pr.M[s];
    totC += pr.C[s];
    float ve = 0.015f * (float)SC[s];
    pr.ve[s] = ve;
    pr.hv[s] = 0.5f * ve;
  }
  pr.off = (-0.5f * 0.015f) * 64.0f;   // exact f32 replication of OFFSET
  pr.totM = totM;
  pr.totC = totC;
  pr.nChunks = (pr.N + 255) / 256;

  // choose partition size; shrink P if workspace is tight
  int chunkTarget = 512;
  int partTriples = 0, blocks = 0;
  for (int attempt = 0; attempt < 10; ++attempt) {
    partTriples = 0; blocks = 0;
    for (int s = 0; s < 4; ++s) {
      int P = (pr.M[s] + chunkTarget - 1) / chunkTarget;
      if (P < 1) P = 1;
      pr.P[s] = P;
      pr.chunkLen[s] = (pr.M[s] + P - 1) / P;
      pr.blkStart[s] = blocks;
      blocks += P * pr.nChunks;
      pr.partOff[s] = partTriples * 3;
      partTriples += P * pr.N;
    }
    pr.blkStart[4] = blocks;
    size_t need = (size_t)totM * 16 + (size_t)partTriples * 3 * 8
                + (size_t)4 * pr.N * 3 * 8 + (size_t)pr.N * 4;
    if (need <= ws_size || chunkTarget >= 64000) break;
    chunkTarget *= 4;
  }

  char* ws = (char*)d_ws;
  size_t o = 0;
  pr.centers = (float4*)(ws + o); o += (size_t)totM * 16;
  pr.partD = (float*)(ws + o);    o += (size_t)partTriples * 3 * 4;
  pr.partI = (int*)(ws + o);      o += (size_t)partTriples * 3 * 4;
  pr.wfin = (float*)(ws + o);     o += (size_t)4 * pr.N * 3 * 4;
  pr.ifin = (int*)(ws + o);       o += (size_t)4 * pr.N * 3 * 4;
  pr.perm = (int*)(ws + o);       o += (size_t)pr.N * 4;
  pr.outp = (float*)d_out;

  hipLaunchKernelGGL(centers_kernel, dim3((totM + 255) / 256), dim3(256), 0, stream, pr);
  hipLaunchKernelGGL(sort_kernel, dim3(1), dim3(1024), 0, stream, pr);
  hipLaunchKernelGGL(scan_kernel, dim3(blocks), dim3(256), 0, stream, pr);
  hipLaunchKernelGGL(merge_kernel, dim3((4 * pr.N + 255) / 256), dim3(256), 0, stream, pr);
  hipLaunchKernelGGL(gather_kernel, dim3(pr.N), dim3(128), 0, stream, pr);
}

// Round 3
// 177.558 us; speedup vs baseline: 1.4100x; 1.0386x over previous
//
#include <hip/hip_runtime.h>

#define INF_F 3.402823466e+38f

struct Params {
  const float* points;
  const int* idx[4];
  const float* feats[4];
  float4* centers;
  float* partD;
  int* partI;
  int* perm;
  float* outp;
  int N, totM, totC, nChP, cenBlocks;
  int M[4], C[4], cenOff[4], P[4], chunkLen[4], partOff[4], colOff[4], blkStart[5];
  float ve[4], hv[4];
  float off;
};

// ---------------- Morton bucket ---------------------------------------------
__device__ __forceinline__ int spread3(int v) {
  return (v & 1) | ((v & 2) << 2) | ((v & 4) << 4) | ((v & 8) << 6);
}
__device__ __forceinline__ int point_bucket(const float* pts, int i) {
  float x = pts[i * 3 + 0], y = pts[i * 3 + 1], z = pts[i * 3 + 2];
  float sc = 16.0f / 0.96f;
  int cx = (int)((x + 0.48f) * sc);
  int cy = (int)((y + 0.48f) * sc);
  int cz = (int)((z + 0.48f) * sc);
  cx = cx < 0 ? 0 : (cx > 15 ? 15 : cx);
  cy = cy < 0 ? 0 : (cy > 15 ? 15 : cy);
  cz = cz < 0 ? 0 : (cz > 15 ? 15 : cz);
  return spread3(cx) | (spread3(cy) << 1) | (spread3(cz) << 2);  // 12-bit morton
}

// ---------------- kernel 1: centers (blocks 0..cenBlocks-1) + sort (last) ---
__global__ __launch_bounds__(1024) void censort_kernel(Params pr) {
#pragma clang fp contract(off)
  if ((int)blockIdx.x < pr.cenBlocks) {
    int t = blockIdx.x * 1024 + threadIdx.x;
    if (t >= pr.totM) return;
    int s = (t >= pr.cenOff[1]) + (t >= pr.cenOff[2]) + (t >= pr.cenOff[3]);
    int m = t - pr.cenOff[s];
    const int* id = pr.idx[s] + (size_t)m * 4;
    float ve = pr.ve[s], hv = pr.hv[s], off = pr.off;
    float4 q;
    q.x = ((float)id[1] * ve + off) + hv;   // exact reference op order, no fma
    q.y = ((float)id[2] * ve + off) + hv;
    q.z = ((float)id[3] * ve + off) + hv;
    q.w = 0.0f;
    pr.centers[t] = q;
    return;
  }
  // ---- sort block: 1024 threads ----
  __shared__ int hist[4096];
  __shared__ int wtot[16];
  int tid = threadIdx.x;
  for (int i = tid; i < 4096; i += 1024) hist[i] = 0;
  __syncthreads();
  for (int i = tid; i < pr.N; i += 1024)
    atomicAdd(&hist[point_bucket(pr.points, i)], 1);
  __syncthreads();
  // hierarchical exclusive scan of hist[4096]: 4 entries per thread
  int h0 = hist[4 * tid + 0], h1 = hist[4 * tid + 1];
  int h2 = hist[4 * tid + 2], h3 = hist[4 * tid + 3];
  int mySum = h0 + h1 + h2 + h3;
  int lane = tid & 63, wv = tid >> 6;
  int inc = mySum;
  for (int off = 1; off < 64; off <<= 1) {
    int u = __shfl_up(inc, off);
    if (lane >= off) inc += u;
  }
  if (lane == 63) wtot[wv] = inc;
  __syncthreads();
  int wbase = 0;
  for (int w = 0; w < 16; ++w) wbase += (w < wv) ? wtot[w] : 0;
  int excl = wbase + inc - mySum;
  hist[4 * tid + 0] = excl;
  hist[4 * tid + 1] = excl + h0;
  hist[4 * tid + 2] = excl + h0 + h1;
  hist[4 * tid + 3] = excl + h0 + h1 + h2;
  __syncthreads();
  for (int i = tid; i < pr.N; i += 1024) {
    int pos = atomicAdd(&hist[point_bucket(pr.points, i)], 1);
    pr.perm[pos] = i;
  }
}

// ---------------- kernel 2: scan, 4 points per thread ------------------------
#define STAGE_CAP 512

__global__ __launch_bounds__(256) void scan_kernel(Params pr) {
#pragma clang fp contract(off)
  __shared__ float4 lds[STAGE_CAP];
  int b = blockIdx.x;
  int s = (b >= pr.blkStart[1]) + (b >= pr.blkStart[2]) + (b >= pr.blkStart[3]);
  int rel = b - pr.blkStart[s];
  int part = rel / pr.nChP;           // block-uniform
  int chunkP = rel - part * pr.nChP;
  int base = part * pr.chunkLen[s];
  int L = pr.M[s] - base;
  if (L > pr.chunkLen[s]) L = pr.chunkLen[s];
  const float4* cen = pr.centers + pr.cenOff[s] + base;

  int n[4]; bool act[4];
  float px[4], py[4], pz[4];
  float bd[4][3]; int bi[4][3];
#pragma unroll
  for (int p = 0; p < 4; ++p) {
    n[p] = chunkP * 1024 + p * 256 + threadIdx.x;
    act[p] = n[p] < pr.N;
    int pid = act[p] ? pr.perm[n[p]] : 0;
    px[p] = pr.points[pid * 3 + 0];
    py[p] = pr.points[pid * 3 + 1];
    pz[p] = pr.points[pid * 3 + 2];
    bd[p][0] = INF_F; bd[p][1] = INF_F; bd[p][2] = INF_F;
    bi[p][0] = 0; bi[p][1] = 0; bi[p][2] = 0;
  }

  auto ins = [](float d, int gi, float& b0, float& b1, float& b2,
                int& i0, int& i1, int& i2) {
    bool lt1 = d < b1, lt0 = d < b0;   // strict <: stable (lowest-index) tie-break
    b2 = lt1 ? b1 : d;  i2 = lt1 ? i1 : gi;
    b1 = lt0 ? b0 : (lt1 ? d : b1);
    i1 = lt0 ? i0 : (lt1 ? gi : i1);
    b0 = lt0 ? d : b0;  i0 = lt0 ? gi : i0;
  };

  for (int cb = 0; cb < L; cb += STAGE_CAP) {
    int Lc = L - cb;
    if (Lc > STAGE_CAP) Lc = STAGE_CAP;
    __syncthreads();
    for (int jj = threadIdx.x; jj < Lc; jj += 256) lds[jj] = cen[cb + jj];
    __syncthreads();
    int gbase = base + cb;
    int j = 0;
    for (; j + 4 <= Lc; j += 4) {
      float4 q0 = lds[j + 0], q1 = lds[j + 1], q2 = lds[j + 2], q3 = lds[j + 3];
#pragma unroll
      for (int p = 0; p < 4; ++p) {
        float dx0 = px[p] - q0.x, dy0 = py[p] - q0.y, dz0 = pz[p] - q0.z;
        float dx1 = px[p] - q1.x, dy1 = py[p] - q1.y, dz1 = pz[p] - q1.z;
        float dx2 = px[p] - q2.x, dy2 = py[p] - q2.y, dz2 = pz[p] - q2.z;
        float dx3 = px[p] - q3.x, dy3 = py[p] - q3.y, dz3 = pz[p] - q3.z;
        float d0 = (dx0 * dx0 + dy0 * dy0) + dz0 * dz0;   // reference op order
        float d1 = (dx1 * dx1 + dy1 * dy1) + dz1 * dz1;
        float d2 = (dx2 * dx2 + dy2 * dy2) + dz2 * dz2;
        float d3 = (dx3 * dx3 + dy3 * dy3) + dz3 * dz3;
        float m = fminf(fminf(d0, d1), fminf(d2, d3));
        if (m < bd[p][2]) {
          if (d0 < bd[p][2]) ins(d0, gbase + j + 0, bd[p][0], bd[p][1], bd[p][2], bi[p][0], bi[p][1], bi[p][2]);
          if (d1 < bd[p][2]) ins(d1, gbase + j + 1, bd[p][0], bd[p][1], bd[p][2], bi[p][0], bi[p][1], bi[p][2]);
          if (d2 < bd[p][2]) ins(d2, gbase + j + 2, bd[p][0], bd[p][1], bd[p][2], bi[p][0], bi[p][1], bi[p][2]);
          if (d3 < bd[p][2]) ins(d3, gbase + j + 3, bd[p][0], bd[p][1], bd[p][2], bi[p][0], bi[p][1], bi[p][2]);
        }
      }
    }
    for (; j < Lc; ++j) {
      float4 q = lds[j];
#pragma unroll
      for (int p = 0; p < 4; ++p) {
        float dx = px[p] - q.x, dy = py[p] - q.y, dz = pz[p] - q.z;
        float d = (dx * dx + dy * dy) + dz * dz;
        if (d < bd[p][2])
          ins(d, gbase + j, bd[p][0], bd[p][1], bd[p][2], bi[p][0], bi[p][1], bi[p][2]);
      }
    }
  }

#pragma unroll
  for (int p = 0; p < 4; ++p) {
    if (act[p]) {
      size_t po = (size_t)pr.partOff[s] + ((size_t)part * pr.N + n[p]) * 3;
      pr.partD[po + 0] = bd[p][0]; pr.partD[po + 1] = bd[p][1]; pr.partD[po + 2] = bd[p][2];
      pr.partI[po + 0] = bi[p][0]; pr.partI[po + 1] = bi[p][1]; pr.partI[po + 2] = bi[p][2];
    }
  }
}

// ---------------- kernel 3: fused merge + gather (block per point) ----------
__device__ __forceinline__ bool lexlt(float da, int ia, float db, int ib) {
  return da < db || (da == db && ia < ib);
}

__global__ __launch_bounds__(256) void mergegather_kernel(Params pr) {
#pragma clang fp contract(off)
  __shared__ float wsh[4][3];
  __shared__ int ish[4][3];
  int nslot = blockIdx.x;
  int tid = threadIdx.x;
  int lane = tid & 63, s = tid >> 6;   // wave s handles scale s

  // phase 1: lane p loads partial p's lex-sorted triple; butterfly top-3 merge
  float d0 = INF_F, d1 = INF_F, d2 = INF_F;
  int i0 = 0, i1 = 0, i2 = 0;
  if (lane < pr.P[s]) {
    size_t po = (size_t)pr.partOff[s] + ((size_t)lane * pr.N + nslot) * 3;
    d0 = pr.partD[po + 0]; d1 = pr.partD[po + 1]; d2 = pr.partD[po + 2];
    i0 = pr.partI[po + 0]; i1 = pr.partI[po + 1]; i2 = pr.partI[po + 2];
  }
#pragma unroll
  for (int off = 1; off < 64; off <<= 1) {
    float od0 = __shfl_xor(d0, off), od1 = __shfl_xor(d1, off), od2 = __shfl_xor(d2, off);
    int oi0 = __shfl_xor(i0, off), oi1 = __shfl_xor(i1, off), oi2 = __shfl_xor(i2, off);
    bool bw = lexlt(od0, oi0, d0, i0);               // other list wins head?
    float xd0 = bw ? od0 : d0, xd1 = bw ? od1 : d1, xd2 = bw ? od2 : d2;
    int   xi0 = bw ? oi0 : i0, xi1 = bw ? oi1 : i1, xi2 = bw ? oi2 : i2;
    float yd0 = bw ? d0 : od0, yd1 = bw ? d1 : od1;
    int   yi0 = bw ? i0 : oi0, yi1 = bw ? i1 : oi1;
    bool x1w = lexlt(xd1, xi1, yd0, yi0);
    bool a2 = lexlt(xd2, xi2, yd0, yi0);
    bool c2 = lexlt(xd1, xi1, yd1, yi1);
    d0 = xd0; i0 = xi0;
    d1 = x1w ? xd1 : yd0;  i1 = x1w ? xi1 : yi0;
    d2 = x1w ? (a2 ? xd2 : yd0) : (c2 ? xd1 : yd1);
    i2 = x1w ? (a2 ? xi2 : yi0) : (c2 ? xi1 : yi1);
  }
  if (lane == 0) {
    float r0 = 1.0f / (d0 + 1e-8f);
    float r1 = 1.0f / (d1 + 1e-8f);
    float r2 = 1.0f / (d2 + 1e-8f);
    float sum = (r0 + r1) + r2;
    wsh[s][0] = r0 / sum; wsh[s][1] = r1 / sum; wsh[s][2] = r2 / sum;
    ish[s][0] = i0; ish[s][1] = i1; ish[s][2] = i2;
  }
  __syncthreads();

  // phase 2: gather totC/4 float4 columns
  int pid = pr.perm[nslot];
  int nC4 = pr.totC >> 2;
  for (int c4 = tid; c4 < nC4; c4 += 256) {
    int c = c4 << 2;
    int gs = (c >= pr.colOff[1]) + (c >= pr.colOff[2]) + (c >= pr.colOff[3]);
    int cc = c - pr.colOff[gs];
    float w0 = wsh[gs][0], w1 = wsh[gs][1], w2 = wsh[gs][2];
    int g0 = ish[gs][0], g1 = ish[gs][1], g2 = ish[gs][2];
    const float* F = pr.feats[gs];
    int C = pr.C[gs];
    const float4 a = *(const float4*)(F + (size_t)g0 * C + cc);
    const float4 bq = *(const float4*)(F + (size_t)g1 * C + cc);
    const float4 cq = *(const float4*)(F + (size_t)g2 * C + cc);
    float4 v;
    v.x = (w0 * a.x + w1 * bq.x) + w2 * cq.x;
    v.y = (w0 * a.y + w1 * bq.y) + w2 * cq.y;
    v.z = (w0 * a.z + w1 * bq.z) + w2 * cq.z;
    v.w = (w0 * a.w + w1 * bq.w) + w2 * cq.w;
    *(float4*)(pr.outp + (size_t)pid * pr.totC + c) = v;
  }
}

extern "C" void kernel_launch(void* const* d_in, const int* in_sizes, int n_in,
                              void* d_out, int out_size, void* d_ws, size_t ws_size,
                              hipStream_t stream) {
  (void)n_in; (void)out_size;
  Params pr;
  pr.points = (const float*)d_in[0];
  pr.N = in_sizes[0] / 3;
  static const int SC[4] = {2, 4, 8, 16};
  int totM = 0, totC = 0;
  for (int s = 0; s < 4; ++s) {
    pr.idx[s] = (const int*)d_in[2 + 2 * s];
    pr.feats[s] = (const float*)d_in[3 + 2 * s];
    pr.M[s] = in_sizes[2 + 2 * s] / 4;
    pr.C[s] = in_sizes[3 + 2 * s] / pr.M[s];
    pr.cenOff[s] = totM;
    pr.colOff[s] = totC;
    totM += pr.M[s];
    totC += pr.C[s];
    float ve = 0.015f * (float)SC[s];
    pr.ve[s] = ve;
    pr.hv[s] = 0.5f * ve;
  }
  pr.off = (-0.5f * 0.015f) * 64.0f;   // exact f32 replication of OFFSET
  pr.totM = totM;
  pr.totC = totC;
  pr.nChP = (pr.N + 1023) / 1024;

  // partition sizing: chunkTarget >= M/64 so P <= 64 lanes (butterfly merge);
  // grow if workspace is tight
  int chunkTarget = 256;
  int partTriples = 0, blocks = 0;
  for (int attempt = 0; attempt < 10; ++attempt) {
    partTriples = 0; blocks = 0;
    for (int s = 0; s < 4; ++s) {
      int P = (pr.M[s] + chunkTarget - 1) / chunkTarget;
      if (P < 1) P = 1;
      if (P > 64) P = 64;
      pr.P[s] = P;
      pr.chunkLen[s] = (pr.M[s] + P - 1) / P;
      pr.blkStart[s] = blocks;
      blocks += P * pr.nChP;
      pr.partOff[s] = partTriples * 3;
      partTriples += P * pr.N;
    }
    pr.blkStart[4] = blocks;
    size_t need = (size_t)totM * 16 + (size_t)partTriples * 3 * 8 + (size_t)pr.N * 4;
    if (need <= ws_size || chunkTarget >= 64000) break;
    chunkTarget *= 4;
  }

  char* ws = (char*)d_ws;
  size_t o = 0;
  pr.centers = (float4*)(ws + o); o += (size_t)totM * 16;
  pr.partD = (float*)(ws + o);    o += (size_t)partTriples * 3 * 4;
  pr.partI = (int*)(ws + o);      o += (size_t)partTriples * 3 * 4;
  pr.perm = (int*)(ws + o);       o += (size_t)pr.N * 4;
  pr.outp = (float*)d_out;

  pr.cenBlocks = (totM + 1023) / 1024;
  hipLaunchKernelGGL(censort_kernel, dim3(pr.cenBlocks + 1), dim3(1024), 0, stream, pr);
  hipLaunchKernelGGL(scan_kernel, dim3(blocks), dim3(256), 0, stream, pr);
  hipLaunchKernelGGL(mergegather_kernel, dim3(pr.N), dim3(256), 0, stream, pr);
}

// Round 4
// 157.126 us; speedup vs baseline: 1.5933x; 1.1300x over previous
//
#include <hip/hip_runtime.h>

#define INF_F 3.402823466e+38f

struct Params {
  const float* points;
  const int* idx[4];
  const float* feats[4];
  float4* centers;
  float2* part;        // [scale][slot n][partition p] triples of (d, idx-as-float)
  int* perm;
  float* outp;
  int N, totM, totC, nChP, cenBlocks;
  int M[4], C[4], cenOff[4], P[4], chunkLen[4], partOff[4], colOff[4], blkStart[5];
  float ve[4], hv[4];
  float off;
};

// ---------------- Morton bucket ---------------------------------------------
__device__ __forceinline__ int spread3(int v) {
  return (v & 1) | ((v & 2) << 2) | ((v & 4) << 4) | ((v & 8) << 6);
}
__device__ __forceinline__ int point_bucket(const float* pts, int i) {
  float x = pts[i * 3 + 0], y = pts[i * 3 + 1], z = pts[i * 3 + 2];
  float sc = 16.0f / 0.96f;
  int cx = (int)((x + 0.48f) * sc);
  int cy = (int)((y + 0.48f) * sc);
  int cz = (int)((z + 0.48f) * sc);
  cx = cx < 0 ? 0 : (cx > 15 ? 15 : cx);
  cy = cy < 0 ? 0 : (cy > 15 ? 15 : cy);
  cz = cz < 0 ? 0 : (cz > 15 ? 15 : cz);
  return spread3(cx) | (spread3(cy) << 1) | (spread3(cz) << 2);  // 12-bit morton
}

// ---------------- kernel 1: centers (blocks 0..cenBlocks-1) + sort (last) ---
__global__ __launch_bounds__(1024) void censort_kernel(Params pr) {
#pragma clang fp contract(off)
  if ((int)blockIdx.x < pr.cenBlocks) {
    int t = blockIdx.x * 1024 + threadIdx.x;
    if (t >= pr.totM) return;
    int s = (t >= pr.cenOff[1]) + (t >= pr.cenOff[2]) + (t >= pr.cenOff[3]);
    int m = t - pr.cenOff[s];
    const int* id = pr.idx[s] + (size_t)m * 4;
    float ve = pr.ve[s], hv = pr.hv[s], off = pr.off;
    float4 q;
    q.x = ((float)id[1] * ve + off) + hv;   // exact reference op order, no fma
    q.y = ((float)id[2] * ve + off) + hv;
    q.z = ((float)id[3] * ve + off) + hv;
    q.w = 0.0f;
    pr.centers[t] = q;
    return;
  }
  // ---- sort block: 1024 threads ----
  __shared__ int hist[4096];
  __shared__ int wtot[16];
  int tid = threadIdx.x;
  for (int i = tid; i < 4096; i += 1024) hist[i] = 0;
  __syncthreads();
  for (int i = tid; i < pr.N; i += 1024)
    atomicAdd(&hist[point_bucket(pr.points, i)], 1);
  __syncthreads();
  int h0 = hist[4 * tid + 0], h1 = hist[4 * tid + 1];
  int h2 = hist[4 * tid + 2], h3 = hist[4 * tid + 3];
  int mySum = h0 + h1 + h2 + h3;
  int lane = tid & 63, wv = tid >> 6;
  int inc = mySum;
  for (int off = 1; off < 64; off <<= 1) {
    int u = __shfl_up(inc, off);
    if (lane >= off) inc += u;
  }
  if (lane == 63) wtot[wv] = inc;
  __syncthreads();
  int wbase = 0;
  for (int w = 0; w < 16; ++w) wbase += (w < wv) ? wtot[w] : 0;
  int excl = wbase + inc - mySum;
  hist[4 * tid + 0] = excl;
  hist[4 * tid + 1] = excl + h0;
  hist[4 * tid + 2] = excl + h0 + h1;
  hist[4 * tid + 3] = excl + h0 + h1 + h2;
  __syncthreads();
  for (int i = tid; i < pr.N; i += 1024) {
    int pos = atomicAdd(&hist[point_bucket(pr.points, i)], 1);
    pr.perm[pos] = i;
  }
}

// ---------------- kernel 2: scan, 2 points/thread, 8-candidate groups -------
#define STAGE_CAP 512

__global__ __launch_bounds__(256) void scan_kernel(Params pr) {
#pragma clang fp contract(off)
  __shared__ float4 lds[STAGE_CAP];
  int b = blockIdx.x;
  int s = (b >= pr.blkStart[1]) + (b >= pr.blkStart[2]) + (b >= pr.blkStart[3]);
  int rel = b - pr.blkStart[s];
  int part = rel / pr.nChP;           // block-uniform
  int chunkP = rel - part * pr.nChP;
  int P = pr.P[s];
  int base = part * pr.chunkLen[s];
  int L = pr.M[s] - base;
  if (L > pr.chunkLen[s]) L = pr.chunkLen[s];
  const float4* cen = pr.centers + pr.cenOff[s] + base;

  int n[2]; bool act[2];
  float px[2], py[2], pz[2];
  float bd[2][3]; int bi[2][3];
#pragma unroll
  for (int p = 0; p < 2; ++p) {
    n[p] = chunkP * 512 + p * 256 + threadIdx.x;
    act[p] = n[p] < pr.N;
    int pid = act[p] ? pr.perm[n[p]] : 0;
    px[p] = pr.points[pid * 3 + 0];
    py[p] = pr.points[pid * 3 + 1];
    pz[p] = pr.points[pid * 3 + 2];
    bd[p][0] = INF_F; bd[p][1] = INF_F; bd[p][2] = INF_F;
    bi[p][0] = 0; bi[p][1] = 0; bi[p][2] = 0;
  }

  auto ins = [](float d, int gi, float& b0, float& b1, float& b2,
                int& i0, int& i1, int& i2) {
    bool lt1 = d < b1, lt0 = d < b0;   // strict <: stable (lowest-index) tie-break
    b2 = lt1 ? b1 : d;  i2 = lt1 ? i1 : gi;
    b1 = lt0 ? b0 : (lt1 ? d : b1);
    i1 = lt0 ? i0 : (lt1 ? gi : i1);
    b0 = lt0 ? d : b0;  i0 = lt0 ? gi : i0;
  };

  for (int cb = 0; cb < L; cb += STAGE_CAP) {
    int Lc = L - cb;
    if (Lc > STAGE_CAP) Lc = STAGE_CAP;
    __syncthreads();
    for (int jj = threadIdx.x; jj < Lc; jj += 256) lds[jj] = cen[cb + jj];
    __syncthreads();
    int gbase = base + cb;
    int j = 0;
    for (; j + 8 <= Lc; j += 8) {
      float4 q[8];
#pragma unroll
      for (int k = 0; k < 8; ++k) q[k] = lds[j + k];
#pragma unroll
      for (int p = 0; p < 2; ++p) {
        float d[8];
#pragma unroll
        for (int k = 0; k < 8; ++k) {
          float dx = px[p] - q[k].x, dy = py[p] - q[k].y, dz = pz[p] - q[k].z;
          d[k] = fmaf(dz, dz, fmaf(dy, dy, dx * dx));   // ((dx^2)+dy^2)+dz^2 order
        }
        float m = fminf(fminf(fminf(d[0], d[1]), fminf(d[2], d[3])),
                        fminf(fminf(d[4], d[5]), fminf(d[6], d[7])));
        if (m < bd[p][2]) {
#pragma unroll
          for (int k = 0; k < 8; ++k)
            if (d[k] < bd[p][2])
              ins(d[k], gbase + j + k, bd[p][0], bd[p][1], bd[p][2],
                  bi[p][0], bi[p][1], bi[p][2]);
        }
      }
    }
    for (; j < Lc; ++j) {
      float4 qq = lds[j];
#pragma unroll
      for (int p = 0; p < 2; ++p) {
        float dx = px[p] - qq.x, dy = py[p] - qq.y, dz = pz[p] - qq.z;
        float d = fmaf(dz, dz, fmaf(dy, dy, dx * dx));
        if (d < bd[p][2])
          ins(d, gbase + j, bd[p][0], bd[p][1], bd[p][2],
              bi[p][0], bi[p][1], bi[p][2]);
      }
    }
  }

#pragma unroll
  for (int p = 0; p < 2; ++p) {
    if (act[p]) {
      size_t po = (size_t)pr.partOff[s] + ((size_t)n[p] * P + part) * 3;
      pr.part[po + 0] = make_float2(bd[p][0], __int_as_float(bi[p][0]));
      pr.part[po + 1] = make_float2(bd[p][1], __int_as_float(bi[p][1]));
      pr.part[po + 2] = make_float2(bd[p][2], __int_as_float(bi[p][2]));
    }
  }
}

// ---------------- kernel 3: fused merge + gather (block per point) ----------
__device__ __forceinline__ bool lexlt(float da, int ia, float db, int ib) {
  return da < db || (da == db && ia < ib);
}

__global__ __launch_bounds__(256) void mergegather_kernel(Params pr) {
#pragma clang fp contract(off)
  __shared__ float wsh[4][3];
  __shared__ int ish[4][3];
  int nslot = blockIdx.x;
  int tid = threadIdx.x;
  int lane = tid & 63, s = tid >> 6;   // wave s handles scale s

  // phase 1: lane p loads partial p's lex-sorted triple (contiguous 24B);
  // butterfly top-3 merge
  int P = pr.P[s];
  float d0 = INF_F, d1 = INF_F, d2 = INF_F;
  int i0 = 0, i1 = 0, i2 = 0;
  if (lane < P) {
    size_t po = (size_t)pr.partOff[s] + ((size_t)nslot * P + lane) * 3;
    float2 a0 = pr.part[po + 0], a1 = pr.part[po + 1], a2 = pr.part[po + 2];
    d0 = a0.x; i0 = __float_as_int(a0.y);
    d1 = a1.x; i1 = __float_as_int(a1.y);
    d2 = a2.x; i2 = __float_as_int(a2.y);
  }
#pragma unroll
  for (int off = 1; off < 64; off <<= 1) {
    float od0 = __shfl_xor(d0, off), od1 = __shfl_xor(d1, off), od2 = __shfl_xor(d2, off);
    int oi0 = __shfl_xor(i0, off), oi1 = __shfl_xor(i1, off), oi2 = __shfl_xor(i2, off);
    bool bw = lexlt(od0, oi0, d0, i0);               // other list wins head?
    float xd0 = bw ? od0 : d0, xd1 = bw ? od1 : d1, xd2 = bw ? od2 : d2;
    int   xi0 = bw ? oi0 : i0, xi1 = bw ? oi1 : i1, xi2 = bw ? oi2 : i2;
    float yd0 = bw ? d0 : od0, yd1 = bw ? d1 : od1;
    int   yi0 = bw ? i0 : oi0, yi1 = bw ? i1 : oi1;
    bool x1w = lexlt(xd1, xi1, yd0, yi0);
    bool a2 = lexlt(xd2, xi2, yd0, yi0);
    bool c2 = lexlt(xd1, xi1, yd1, yi1);
    d0 = xd0; i0 = xi0;
    d1 = x1w ? xd1 : yd0;  i1 = x1w ? xi1 : yi0;
    d2 = x1w ? (a2 ? xd2 : yd0) : (c2 ? xd1 : yd1);
    i2 = x1w ? (a2 ? xi2 : yi0) : (c2 ? xi1 : yi1);
  }
  if (lane == 0) {
    float r0 = 1.0f / (d0 + 1e-8f);
    float r1 = 1.0f / (d1 + 1e-8f);
    float r2 = 1.0f / (d2 + 1e-8f);
    float sum = (r0 + r1) + r2;
    wsh[s][0] = r0 / sum; wsh[s][1] = r1 / sum; wsh[s][2] = r2 / sum;
    ish[s][0] = i0; ish[s][1] = i1; ish[s][2] = i2;
  }
  __syncthreads();

  // phase 2: gather totC/4 float4 columns
  int pid = pr.perm[nslot];
  int nC4 = pr.totC >> 2;
  for (int c4 = tid; c4 < nC4; c4 += 256) {
    int c = c4 << 2;
    int gs = (c >= pr.colOff[1]) + (c >= pr.colOff[2]) + (c >= pr.colOff[3]);
    int cc = c - pr.colOff[gs];
    float w0 = wsh[gs][0], w1 = wsh[gs][1], w2 = wsh[gs][2];
    int g0 = ish[gs][0], g1 = ish[gs][1], g2 = ish[gs][2];
    const float* F = pr.feats[gs];
    int C = pr.C[gs];
    const float4 a = *(const float4*)(F + (size_t)g0 * C + cc);
    const float4 bq = *(const float4*)(F + (size_t)g1 * C + cc);
    const float4 cq = *(const float4*)(F + (size_t)g2 * C + cc);
    float4 v;
    v.x = (w0 * a.x + w1 * bq.x) + w2 * cq.x;
    v.y = (w0 * a.y + w1 * bq.y) + w2 * cq.y;
    v.z = (w0 * a.z + w1 * bq.z) + w2 * cq.z;
    v.w = (w0 * a.w + w1 * bq.w) + w2 * cq.w;
    *(float4*)(pr.outp + (size_t)pid * pr.totC + c) = v;
  }
}

extern "C" void kernel_launch(void* const* d_in, const int* in_sizes, int n_in,
                              void* d_out, int out_size, void* d_ws, size_t ws_size,
                              hipStream_t stream) {
  (void)n_in; (void)out_size;
  Params pr;
  pr.points = (const float*)d_in[0];
  pr.N = in_sizes[0] / 3;
  static const int SC[4] = {2, 4, 8, 16};
  int totM = 0, totC = 0;
  for (int s = 0; s < 4; ++s) {
    pr.idx[s] = (const int*)d_in[2 + 2 * s];
    pr.feats[s] = (const float*)d_in[3 + 2 * s];
    pr.M[s] = in_sizes[2 + 2 * s] / 4;
    pr.C[s] = in_sizes[3 + 2 * s] / pr.M[s];
    pr.cenOff[s] = totM;
    pr.colOff[s] = totC;
    totM += pr.M[s];
    totC += pr.C[s];
    float ve = 0.015f * (float)SC[s];
    pr.ve[s] = ve;
    pr.hv[s] = 0.5f * ve;
  }
  pr.off = (-0.5f * 0.015f) * 64.0f;   // exact f32 replication of OFFSET
  pr.totM = totM;
  pr.totC = totC;
  pr.nChP = (pr.N + 511) / 512;        // 512 points per block (2 per thread)

  // partition sizing: P <= 64 lanes (butterfly merge); grow chunk if ws tight
  int chunkTarget = 256;
  int partTriples = 0, blocks = 0;
  for (int attempt = 0; attempt < 10; ++attempt) {
    partTriples = 0; blocks = 0;
    for (int s = 0; s < 4; ++s) {
      int P = (pr.M[s] + chunkTarget - 1) / chunkTarget;
      if (P < 1) P = 1;
      if (P > 64) P = 64;
      pr.P[s] = P;
      pr.chunkLen[s] = (pr.M[s] + P - 1) / P;
      pr.blkStart[s] = blocks;
      blocks += P * pr.nChP;
      pr.partOff[s] = partTriples * 3;       // float2-element offset
      partTriples += P * pr.N;
    }
    pr.blkStart[4] = blocks;
    size_t need = (size_t)totM * 16 + (size_t)partTriples * 3 * 8 + (size_t)pr.N * 4;
    if (need <= ws_size || chunkTarget >= 64000) break;
    chunkTarget *= 4;
  }

  char* ws = (char*)d_ws;
  size_t o = 0;
  pr.centers = (float4*)(ws + o); o += (size_t)totM * 16;
  pr.part = (float2*)(ws + o);    o += (size_t)partTriples * 3 * 8;
  pr.perm = (int*)(ws + o);       o += (size_t)pr.N * 4;
  pr.outp = (float*)d_out;

  pr.cenBlocks = (totM + 1023) / 1024;
  hipLaunchKernelGGL(censort_kernel, dim3(pr.cenBlocks + 1), dim3(1024), 0, stream, pr);
  hipLaunchKernelGGL(scan_kernel, dim3(blocks), dim3(256), 0, stream, pr);
  hipLaunchKernelGGL(mergegather_kernel, dim3(pr.N), dim3(256), 0, stream, pr);
}